// Round 9
// baseline (110.206 us; speedup 1.0000x reference)
//
#include <hip/hip_runtime.h>

constexpr int B = 8;
constexpr int A = 49104;
constexpr int C = 90;
constexpr int M = 32;
constexpr float EPS_CLIP = 1e-4f;
constexpr float LN2 = 0.6931471805599453f;

constexpr int TPB = 256;
constexpr int N4_TOT = B * A * C / 4;               // 8,838,720 float4 total
constexpr int N4_IMG = A * C / 4;                   // 1,104,840 float4 per image
constexpr int SL4 = 4096;                           // float4 per block slice (64 KB)
constexpr int NBLK = (N4_TOT + SL4 - 1) / SL4;      // 2158
constexpr int ABPI = (A + TPB - 1) / TPB;           // 192 anchor-blocks per image
constexpr int NABLK = ABPI * B;                     // 1536
constexpr int PBLK = 2048;                          // probe blocks

typedef float f32x4 __attribute__((ext_vector_type(4)));

// accum (d_ws): [0..B) S (log2 domain), [B..2B) corr, [2B..3B) reg_sum, [3B..4B) pos_cnt,
//               [32] probe sink (unused by finalize)

__device__ __forceinline__ float clampp(float v) {
    return fminf(fmaxf(v, EPS_CLIP), 1.f - EPS_CLIP);
}

__device__ __forceinline__ float neg4(f32x4 v) {
    float s = 0.f;
#pragma unroll
    for (int j = 0; j < 4; ++j) {
        const float p = clampp(v[j]);
        s = fmaf(p * p, __log2f(1.f - p), s);
    }
    return s;
}

__global__ __launch_bounds__(TPB) void focal_main_kernel(
    const float* __restrict__ cls,   // [B, A, C]
    const float* __restrict__ reg,   // [B, A, 4]
    const float* __restrict__ anc,   // [A, 4]
    const float* __restrict__ ann,   // [B, M, 5]
    float* __restrict__ accum)
{
    __shared__ float s_ann[M * 5];
    __shared__ float s_red[3][TPB / 64];
    __shared__ int   s_list[TPB];
    __shared__ int   s_cnt;

    const int t    = threadIdx.x;
    const int wid  = t >> 6;
    const int lane = t & 63;
    const int blk  = blockIdx.x;

    // ================= Anchor phase (blocks 0..NABLK-1 only) =================
    if (blk < NABLK) {
        const int b     = blk / ABPI;
        const int abase = (blk - b * ABPI) * TPB;

        if (t < M * 5) s_ann[t] = ann[b * M * 5 + t];
        if (t == 0) s_cnt = 0;
        __syncthreads();

        float corr = 0.f, reg_sum = 0.f, pos_cnt = 0.f;
        const int a = abase + t;
        if (a < A) {
            const float4 ab = reinterpret_cast<const float4*>(anc)[a];
            const float aw = ab.z - ab.x;
            const float ah = ab.w - ab.y;
            const float areaA = aw * ah;

            float best = -INFINITY;
            int argm = 0;
            for (int m = 0; m < M; ++m) {
                const float bx1 = s_ann[m * 5 + 0];
                const float by1 = s_ann[m * 5 + 1];
                const float bx2 = s_ann[m * 5 + 2];
                const float by2 = s_ann[m * 5 + 3];
                const float lab = s_ann[m * 5 + 4];
                float iw = fminf(ab.z, bx2) - fmaxf(ab.x, bx1);
                float ih = fminf(ab.w, by2) - fmaxf(ab.y, by1);
                iw = fmaxf(iw, 0.f);
                ih = fmaxf(ih, 0.f);
                const float inter = iw * ih;
                const float ua = fmaxf(areaA + (bx2 - bx1) * (by2 - by1) - inter, 1e-8f);
                const float iou = inter / ua;
                const float val = (lab != -1.0f) ? iou : -1.0f;
                if (val > best) { best = val; argm = m; }   // strict > == first argmax
            }

            if (best >= 0.5f) {
                pos_cnt = 1.f;
                const float gx1 = s_ann[argm * 5 + 0];
                const float gy1 = s_ann[argm * 5 + 1];
                const float gx2 = s_ann[argm * 5 + 2];
                const float gy2 = s_ann[argm * 5 + 3];
                const float acx = ab.x + 0.5f * aw;
                const float acy = ab.y + 0.5f * ah;
                const float gw0 = gx2 - gx1;
                const float gh0 = gy2 - gy1;
                const float gcx = gx1 + 0.5f * gw0;
                const float gcy = gy1 + 0.5f * gh0;
                const float gw = fmaxf(gw0, 1.f);
                const float gh = fmaxf(gh0, 1.f);
                const float4 rp = reinterpret_cast<const float4*>(reg)[(size_t)b * A + a];
                const float rt0 = (gcx - acx) / aw * 10.f;
                const float rt1 = (gcy - acy) / ah * 10.f;
                const float rt2 = __logf(gw / aw) * 5.f;
                const float rt3 = __logf(gh / ah) * 5.f;
                const float d0 = fabsf(rt0 - rp.x);
                const float d1 = fabsf(rt1 - rp.y);
                const float d2 = fabsf(rt2 - rp.z);
                const float d3 = fabsf(rt3 - rp.w);
                auto sl1 = [](float d) {
                    return (d <= (1.f / 9.f)) ? 4.5f * d * d : d - (0.5f / 9.f);
                };
                reg_sum = sl1(d0) + sl1(d1) + sl1(d2) + sl1(d3);

                const int cidx = (int)s_ann[argm * 5 + 4];
                const float p = clampp(cls[((size_t)b * A + a) * C + cidx]);
                corr = 0.75f * LN2 * (p * p * __log2f(1.f - p))
                     + 0.25f * (1.f - p) * (1.f - p) * (-__logf(p));
            } else if (best >= 0.4f) {
                const int slot = atomicAdd(&s_cnt, 1);
                s_list[slot] = t;
            }
        }
        __syncthreads();

        const int cnt = s_cnt;
        for (int i = wid; i < cnt; i += TPB / 64) {
            const int aidx = s_list[i];
            const float* row = cls + ((size_t)b * A + abase + aidx) * (size_t)C;
            float s = 0.f;
            if (lane < C) {
                const float p = clampp(row[lane]);
                s = p * p * __log2f(1.f - p);
            }
            if (lane + 64 < C) {
                const float p = clampp(row[lane + 64]);
                s = fmaf(p * p, __log2f(1.f - p), s);
            }
            for (int off = 32; off; off >>= 1) s += __shfl_down(s, off);
            if (lane == 0) corr += 0.75f * LN2 * s;
        }

        float v0 = corr, v1 = reg_sum, v2 = pos_cnt;
        for (int off = 32; off; off >>= 1) {
            v0 += __shfl_down(v0, off);
            v1 += __shfl_down(v1, off);
            v2 += __shfl_down(v2, off);
        }
        if (lane == 0) { s_red[0][wid] = v0; s_red[1][wid] = v1; s_red[2][wid] = v2; }
        __syncthreads();
        if (t == 0) {
            float a0 = 0.f, a1 = 0.f, a2 = 0.f;
            for (int w = 0; w < TPB / 64; ++w) {
                a0 += s_red[0][w]; a1 += s_red[1][w]; a2 += s_red[2][w];
            }
            atomicAdd(&accum[B + b],     a0);
            atomicAdd(&accum[2 * B + b], a1);
            atomicAdd(&accum[3 * B + b], a2);
        }
        __syncthreads();   // s_red reused below
    }

    // ================= Stream phase (ALL blocks, uniform, plain loads) =================
    const f32x4* __restrict__ cls4 = reinterpret_cast<const f32x4*>(cls);
    const int sbase = blk * SL4;
    const int nsl   = min(SL4, N4_TOT - sbase);
    const int img0  = sbase / N4_IMG;
    const int imgL  = (sbase + nsl - 1) / N4_IMG;

    float acc0 = 0.f, acc1 = 0.f;
    if (img0 == imgL) {
        const f32x4* p = cls4 + sbase + t;
        int i = t;
        float accA = 0.f, accB = 0.f;
        for (; i + 7 * TPB < nsl; i += 8 * TPB) {
            f32x4 v[8];
#pragma unroll
            for (int k = 0; k < 8; ++k) v[k] = p[k * TPB];
            p += 8 * TPB;
#pragma unroll
            for (int k = 0; k < 8; ++k) {
                if (k & 1) accB += neg4(v[k]); else accA += neg4(v[k]);
            }
        }
        for (; i < nsl; i += TPB) { accA += neg4(*p); p += TPB; }
        acc0 = accA + accB;
    } else {
        const int split = (img0 + 1) * N4_IMG;
        for (int i = t; i < nsl; i += TPB) {
            const float s = neg4(cls4[sbase + i]);
            if (sbase + i < split) acc0 += s; else acc1 += s;
        }
    }

    float w0 = acc0, w1 = acc1;
    for (int off = 32; off; off >>= 1) {
        w0 += __shfl_down(w0, off);
        w1 += __shfl_down(w1, off);
    }
    if (lane == 0) { s_red[0][wid] = w0; s_red[1][wid] = w1; }
    __syncthreads();
    if (t == 0) {
        float a0 = 0.f, a1 = 0.f;
        for (int w = 0; w < TPB / 64; ++w) { a0 += s_red[0][w]; a1 += s_red[1][w]; }
        atomicAdd(&accum[img0], a0);
        if (imgL != img0) atomicAdd(&accum[imgL], a1);
    }
}

// ============ Probe P: textbook pure-read grid-stride float4 sum ============
// Measures what the memory system delivers to an unencumbered reader.
// Result goes to accum[32], never read by finalize (but kept live).
__global__ __launch_bounds__(TPB) void probe_sum_kernel(
    const float* __restrict__ cls, float* __restrict__ accum)
{
    __shared__ float s_red[TPB / 64];
    const f32x4* __restrict__ p4 = reinterpret_cast<const f32x4*>(cls);
    const int tid = blockIdx.x * TPB + threadIdx.x;
    const int stride = PBLK * TPB;

    float a0 = 0.f, a1 = 0.f, a2 = 0.f, a3 = 0.f;
    float a4 = 0.f, a5 = 0.f, a6 = 0.f, a7 = 0.f;
    int i = tid;
    for (; i + 7 * stride < N4_TOT; i += 8 * stride) {
        f32x4 v[8];
#pragma unroll
        for (int k = 0; k < 8; ++k) v[k] = p4[i + k * stride];
        a0 += (v[0].x + v[0].y) + (v[0].z + v[0].w);
        a1 += (v[1].x + v[1].y) + (v[1].z + v[1].w);
        a2 += (v[2].x + v[2].y) + (v[2].z + v[2].w);
        a3 += (v[3].x + v[3].y) + (v[3].z + v[3].w);
        a4 += (v[4].x + v[4].y) + (v[4].z + v[4].w);
        a5 += (v[5].x + v[5].y) + (v[5].z + v[5].w);
        a6 += (v[6].x + v[6].y) + (v[6].z + v[6].w);
        a7 += (v[7].x + v[7].y) + (v[7].z + v[7].w);
    }
    for (; i < N4_TOT; i += stride) {
        const f32x4 v = p4[i];
        a0 += (v.x + v.y) + (v.z + v.w);
    }
    float s = ((a0 + a1) + (a2 + a3)) + ((a4 + a5) + (a6 + a7));
    for (int off = 32; off; off >>= 1) s += __shfl_down(s, off);
    if ((threadIdx.x & 63) == 0) s_red[threadIdx.x >> 6] = s;
    __syncthreads();
    if (threadIdx.x == 0) {
        float t0 = 0.f;
        for (int w = 0; w < TPB / 64; ++w) t0 += s_red[w];
        atomicAdd(&accum[32], t0);
    }
}

// ---------------- Finalize ----------------
__global__ void focal_finalize_kernel(const float* __restrict__ ann,
                                      const float* __restrict__ accum,
                                      float* __restrict__ out)
{
    const int t = threadIdx.x;
    float cls_l = 0.f, reg_l = 0.f;
    if (t < B) {
        bool has = false;
        for (int m = 0; m < M; ++m)
            has = has || (ann[t * M * 5 + m * 5 + 4] != -1.0f);
        const float S    = accum[t];
        const float corr = accum[B + t];
        const float rs   = accum[2 * B + t];
        const float np   = accum[3 * B + t];
        const float cls_sum = -0.75f * LN2 * S + corr;
        cls_l = has ? cls_sum / fmaxf(np, 1.f) : 0.f;
        reg_l = (has && np > 0.f) ? rs / fmaxf(np * 4.f, 1.f) : 0.f;
    }
    for (int off = 4; off; off >>= 1) {
        cls_l += __shfl_down(cls_l, off);
        reg_l += __shfl_down(reg_l, off);
    }
    if (t == 0) {
        out[0] = cls_l * (1.f / B);
        out[1] = reg_l * (1.f / B);
        // keep probe result observable so the probe kernel can't be considered dead
        out[1] += accum[32] * 0.0f;
    }
}

extern "C" void kernel_launch(void* const* d_in, const int* in_sizes, int n_in,
                              void* d_out, int out_size, void* d_ws, size_t ws_size,
                              hipStream_t stream) {
    const float* cls = (const float*)d_in[0];
    const float* reg = (const float*)d_in[1];
    const float* anc = (const float*)d_in[2];
    const float* ann = (const float*)d_in[3];
    float* out = (float*)d_out;
    float* accum = (float*)d_ws;

    (void)hipMemsetAsync(accum, 0, 40 * sizeof(float), stream);

    focal_main_kernel<<<dim3(NBLK), TPB, 0, stream>>>(cls, reg, anc, ann, accum);
    probe_sum_kernel<<<dim3(PBLK), TPB, 0, stream>>>(cls, accum);
    focal_finalize_kernel<<<1, 64, 0, stream>>>(ann, accum, out);
}

// Round 10
// 54.511 us; speedup vs baseline: 2.0217x; 2.0217x over previous
//
#include <hip/hip_runtime.h>

constexpr int B = 8;
constexpr int A = 49104;
constexpr int C = 90;
constexpr int M = 32;
constexpr float EPS_CLIP = 1e-4f;
constexpr float LN2 = 0.6931471805599453f;

constexpr int TPB = 256;
constexpr int N4_TOT = B * A * C / 4;               // 8,838,720 float4 total
constexpr int N4_IMG = A * C / 4;                   // 1,104,840 float4 per image
constexpr int SL4 = 4096;                           // float4 per stream slice (64 KB)
constexpr int NSTREAM = (N4_TOT + SL4 - 1) / SL4;   // 2158
constexpr int APT = 4;                              // anchors per thread
constexpr int AB_ANCH = TPB * APT;                  // 1024 anchors per anchor-block
constexpr int ABPI = (A + AB_ANCH - 1) / AB_ANCH;   // 48 anchor-blocks per image
constexpr int NANCH = ABPI * B;                     // 384

typedef float f32x4 __attribute__((ext_vector_type(4)));

// accum (d_ws): [0..B) S (log2 domain), [B..2B) corr, [2B..3B) reg_sum, [3B..4B) pos_cnt

__device__ __forceinline__ float clampp(float v) {
    return fminf(fmaxf(v, EPS_CLIP), 1.f - EPS_CLIP);   // v_med3_f32
}

__device__ __forceinline__ float neg4(f32x4 v) {
    float s = 0.f;
#pragma unroll
    for (int j = 0; j < 4; ++j) {
        const float p = clampp(v[j]);
        s = fmaf(p * p, __log2f(1.f - p), s);
    }
    return s;
}

__global__ __launch_bounds__(TPB) void focal_main_kernel(
    const float* __restrict__ cls,   // [B, A, C]
    const float* __restrict__ reg,   // [B, A, 4]
    const float* __restrict__ anc,   // [A, 4]
    const float* __restrict__ ann,   // [B, M, 5]
    float* __restrict__ accum)
{
    __shared__ float s_ann[M * 5];
    __shared__ float s_red[3][TPB / 64];
    __shared__ int   s_list[AB_ANCH];
    __shared__ int   s_cnt;

    const int t    = threadIdx.x;
    const int wid  = t >> 6;
    const int lane = t & 63;
    const int blk  = blockIdx.x;

    // ================= Anchor-only blocks (IDs 0..NANCH-1, front of grid) =================
    if (blk < NANCH) {
        const int b     = blk / ABPI;
        const int abase = (blk - b * ABPI) * AB_ANCH;

        if (t < M * 5) s_ann[t] = ann[b * M * 5 + t];
        if (t == 0) s_cnt = 0;
        __syncthreads();

        float corr = 0.f, reg_sum = 0.f, pos_cnt = 0.f;

        float4 ab4[APT];
        float  awk[APT], ahk[APT], areaA[APT], best[APT];
        int    argm[APT];
        bool   act[APT];
#pragma unroll
        for (int k = 0; k < APT; ++k) {
            const int a = abase + t + k * TPB;
            act[k] = (a < A);
            ab4[k] = act[k] ? reinterpret_cast<const float4*>(anc)[a]
                            : make_float4(0.f, 0.f, 0.f, 0.f);
            awk[k] = ab4[k].z - ab4[k].x;
            ahk[k] = ab4[k].w - ab4[k].y;
            areaA[k] = awk[k] * ahk[k];
            best[k] = -INFINITY;
            argm[k] = 0;
        }

        for (int m = 0; m < M; ++m) {
            const float bx1 = s_ann[m * 5 + 0];
            const float by1 = s_ann[m * 5 + 1];
            const float bx2 = s_ann[m * 5 + 2];
            const float by2 = s_ann[m * 5 + 3];
            const float lab = s_ann[m * 5 + 4];
            const float areaB = (bx2 - bx1) * (by2 - by1);
            const bool  vgt = (lab != -1.0f);
#pragma unroll
            for (int k = 0; k < APT; ++k) {
                float iw = fminf(ab4[k].z, bx2) - fmaxf(ab4[k].x, bx1);
                float ih = fminf(ab4[k].w, by2) - fmaxf(ab4[k].y, by1);
                iw = fmaxf(iw, 0.f);
                ih = fmaxf(ih, 0.f);
                const float inter = iw * ih;
                const float ua = fmaxf(areaA[k] + areaB - inter, 1e-8f);
                const float iou = inter / ua;
                const float val = vgt ? iou : -1.0f;
                if (val > best[k]) { best[k] = val; argm[k] = m; }   // strict > == first argmax
            }
        }

#pragma unroll
        for (int k = 0; k < APT; ++k) {
            if (!act[k]) continue;
            const int a = abase + t + k * TPB;
            if (best[k] >= 0.5f) {
                pos_cnt += 1.f;
                const int am = argm[k];
                const float gx1 = s_ann[am * 5 + 0];
                const float gy1 = s_ann[am * 5 + 1];
                const float gx2 = s_ann[am * 5 + 2];
                const float gy2 = s_ann[am * 5 + 3];
                const float acx = ab4[k].x + 0.5f * awk[k];
                const float acy = ab4[k].y + 0.5f * ahk[k];
                const float gw0 = gx2 - gx1;
                const float gh0 = gy2 - gy1;
                const float gcx = gx1 + 0.5f * gw0;
                const float gcy = gy1 + 0.5f * gh0;
                const float gw = fmaxf(gw0, 1.f);
                const float gh = fmaxf(gh0, 1.f);
                const float4 rp = reinterpret_cast<const float4*>(reg)[(size_t)b * A + a];
                const float rt0 = (gcx - acx) / awk[k] * 10.f;
                const float rt1 = (gcy - acy) / ahk[k] * 10.f;
                const float rt2 = __logf(gw / awk[k]) * 5.f;
                const float rt3 = __logf(gh / ahk[k]) * 5.f;
                const float d0 = fabsf(rt0 - rp.x);
                const float d1 = fabsf(rt1 - rp.y);
                const float d2 = fabsf(rt2 - rp.z);
                const float d3 = fabsf(rt3 - rp.w);
                auto sl1 = [](float d) {
                    return (d <= (1.f / 9.f)) ? 4.5f * d * d : d - (0.5f / 9.f);
                };
                reg_sum += sl1(d0) + sl1(d1) + sl1(d2) + sl1(d3);

                const int cidx = (int)s_ann[am * 5 + 4];
                const float p = clampp(cls[((size_t)b * A + a) * C + cidx]);
                corr += 0.75f * LN2 * (p * p * __log2f(1.f - p))      // cancel streamed term
                      + 0.25f * (1.f - p) * (1.f - p) * (-__logf(p)); // true positive term
            } else if (best[k] >= 0.4f) {
                const int slot = atomicAdd(&s_cnt, 1);
                s_list[slot] = t + k * TPB;
            }
        }
        __syncthreads();

        // wave-cooperative coalesced row sums for ignore anchors
        const int cnt = s_cnt;
        for (int i = wid; i < cnt; i += TPB / 64) {
            const int aidx = s_list[i];
            const float* row = cls + ((size_t)b * A + abase + aidx) * (size_t)C;
            float s = 0.f;
            if (lane < C) {
                const float p = clampp(row[lane]);
                s = p * p * __log2f(1.f - p);
            }
            if (lane + 64 < C) {
                const float p = clampp(row[lane + 64]);
                s = fmaf(p * p, __log2f(1.f - p), s);
            }
            for (int off = 32; off; off >>= 1) s += __shfl_down(s, off);
            if (lane == 0) corr += 0.75f * LN2 * s;
        }

        float v0 = corr, v1 = reg_sum, v2 = pos_cnt;
        for (int off = 32; off; off >>= 1) {
            v0 += __shfl_down(v0, off);
            v1 += __shfl_down(v1, off);
            v2 += __shfl_down(v2, off);
        }
        if (lane == 0) { s_red[0][wid] = v0; s_red[1][wid] = v1; s_red[2][wid] = v2; }
        __syncthreads();
        if (t == 0) {
            float a0 = 0.f, a1 = 0.f, a2 = 0.f;
            for (int w = 0; w < TPB / 64; ++w) {
                a0 += s_red[0][w]; a1 += s_red[1][w]; a2 += s_red[2][w];
            }
            atomicAdd(&accum[B + b],     a0);
            atomicAdd(&accum[2 * B + b], a1);
            atomicAdd(&accum[3 * B + b], a2);
        }
        return;
    }

    // ================= Stream-only blocks (uniform 64 KB contiguous slices) =================
    const int sblk = blk - NANCH;
    const f32x4* __restrict__ cls4 = reinterpret_cast<const f32x4*>(cls);
    const int sbase = sblk * SL4;
    const int nsl   = min(SL4, N4_TOT - sbase);
    const int img0  = sbase / N4_IMG;
    const int imgL  = (sbase + nsl - 1) / N4_IMG;

    float acc0 = 0.f, acc1 = 0.f;
    if (img0 == imgL) {
        const f32x4* p = cls4 + sbase + t;
        int i = t;
        float accA = 0.f, accB = 0.f;
        for (; i + 7 * TPB < nsl; i += 8 * TPB) {
            f32x4 v[8];
#pragma unroll
            for (int k = 0; k < 8; ++k) v[k] = p[k * TPB];
            p += 8 * TPB;
#pragma unroll
            for (int k = 0; k < 8; ++k) {
                if (k & 1) accB += neg4(v[k]); else accA += neg4(v[k]);
            }
        }
        for (; i < nsl; i += TPB) { accA += neg4(*p); p += TPB; }
        acc0 = accA + accB;
    } else {
        // image-boundary slice (7 of 2158): per-element image split
        const int split = (img0 + 1) * N4_IMG;
        for (int i = t; i < nsl; i += TPB) {
            const float s = neg4(cls4[sbase + i]);
            if (sbase + i < split) acc0 += s; else acc1 += s;
        }
    }

    float w0 = acc0, w1 = acc1;
    for (int off = 32; off; off >>= 1) {
        w0 += __shfl_down(w0, off);
        w1 += __shfl_down(w1, off);
    }
    if (lane == 0) { s_red[0][wid] = w0; s_red[1][wid] = w1; }
    __syncthreads();
    if (t == 0) {
        float a0 = 0.f, a1 = 0.f;
        for (int w = 0; w < TPB / 64; ++w) { a0 += s_red[0][w]; a1 += s_red[1][w]; }
        atomicAdd(&accum[img0], a0);
        if (imgL != img0) atomicAdd(&accum[imgL], a1);
    }
}

// ---------------- Finalize ----------------
__global__ void focal_finalize_kernel(const float* __restrict__ ann,
                                      const float* __restrict__ accum,
                                      float* __restrict__ out)
{
    const int t = threadIdx.x;
    float cls_l = 0.f, reg_l = 0.f;
    if (t < B) {
        bool has = false;
        for (int m = 0; m < M; ++m)
            has = has || (ann[t * M * 5 + m * 5 + 4] != -1.0f);
        const float S    = accum[t];
        const float corr = accum[B + t];
        const float rs   = accum[2 * B + t];
        const float np   = accum[3 * B + t];
        const float cls_sum = -0.75f * LN2 * S + corr;
        cls_l = has ? cls_sum / fmaxf(np, 1.f) : 0.f;
        reg_l = (has && np > 0.f) ? rs / fmaxf(np * 4.f, 1.f) : 0.f;
    }
    for (int off = 4; off; off >>= 1) {
        cls_l += __shfl_down(cls_l, off);
        reg_l += __shfl_down(reg_l, off);
    }
    if (t == 0) {
        out[0] = cls_l * (1.f / B);
        out[1] = reg_l * (1.f / B);
    }
}

extern "C" void kernel_launch(void* const* d_in, const int* in_sizes, int n_in,
                              void* d_out, int out_size, void* d_ws, size_t ws_size,
                              hipStream_t stream) {
    const float* cls = (const float*)d_in[0];
    const float* reg = (const float*)d_in[1];
    const float* anc = (const float*)d_in[2];
    const float* ann = (const float*)d_in[3];
    float* out = (float*)d_out;
    float* accum = (float*)d_ws;

    (void)hipMemsetAsync(accum, 0, 4 * B * sizeof(float), stream);

    focal_main_kernel<<<dim3(NANCH + NSTREAM), TPB, 0, stream>>>(cls, reg, anc, ann, accum);
    focal_finalize_kernel<<<1, 64, 0, stream>>>(ann, accum, out);
}